// Round 6
// baseline (457.587 us; speedup 1.0000x reference)
//
#include <hip/hip_runtime.h>
#include <hip/hip_bf16.h>

#define T_LEN 2048
#define HID_DIM 2048
#define NH 16
#define NKV 2
#define HD 256
#define ROT 64
#define EPS_F 1e-6f
#define SCALE_F 0.0625f   // 256^-0.5
#define THETA_F 10000000.0f

typedef __bf16 bf16x8 __attribute__((ext_vector_type(8)));
typedef float floatx4 __attribute__((ext_vector_type(4)));

__device__ __forceinline__ unsigned short f2bf(float x) {
  unsigned int u = __float_as_uint(x);
  unsigned int rounding = 0x7FFFu + ((u >> 16) & 1u);
  return (unsigned short)((u + rounding) >> 16);
}
__device__ __forceinline__ float bf2f(unsigned short u) {
  return __uint_as_float(((unsigned int)u) << 16);
}
__device__ __forceinline__ floatx4 mfma16(bf16x8 a, bf16x8 b, floatx4 c) {
  return __builtin_amdgcn_mfma_f32_16x16x32_bf16(a, b, c, 0, 0, 0);
}
// async global->LDS DMA, 16B/lane: lds dest = wave-uniform base + lane*16
__device__ __forceinline__ void gl_lds16(const unsigned short* g, unsigned short* l) {
  __builtin_amdgcn_global_load_lds(
      (const __attribute__((address_space(1))) unsigned int*)g,
      (__attribute__((address_space(3))) unsigned int*)l, 16, 0, 0);
}

// ---------------- merged fp32 -> bf16 conversion (5 segments, f4-vectorized) ----------------
__global__ __launch_bounds__(256) void cvt_all(
    const float* __restrict__ hs, const float* __restrict__ wq,
    const float* __restrict__ wk, const float* __restrict__ wv,
    const float* __restrict__ wo, unsigned short* __restrict__ hsb,
    unsigned short* __restrict__ qkvwb, unsigned short* __restrict__ wob) {
  int i = blockIdx.x * 256 + threadIdx.x;  // float4 index, total 7864320
  const float4* s4;
  ushort4* d4;
  int j;
  if (i < 1048576) { s4 = (const float4*)hs; d4 = (ushort4*)hsb; j = i; }
  else if (i < 5242880) { s4 = (const float4*)wq; d4 = (ushort4*)qkvwb; j = i - 1048576; }
  else if (i < 5505024) { s4 = (const float4*)wk; d4 = (ushort4*)qkvwb + 4194304; j = i - 5242880; }
  else if (i < 5767168) { s4 = (const float4*)wv; d4 = (ushort4*)qkvwb + 4456448; j = i - 5505024; }
  else { s4 = (const float4*)wo; d4 = (ushort4*)wob; j = i - 5767168; }
  float4 v = s4[j];
  ushort4 o;
  o.x = f2bf(v.x); o.y = f2bf(v.y); o.z = f2bf(v.z); o.w = f2bf(v.w);
  d4[j] = o;
}

// ---------------- bf16 GEMM: C[M,N] = A[M,K] * B[N,K]^T ----------------
// ld = row stride of A and B (elements); Ksub = K-range per z-slice.
// blockIdx.z selects K-slice [z*Ksub, (z+1)*Ksub); fp32 path writes partial
// z to Cv + z*M*N (split-K for TLP when M/128 * N/128 < 2*256 CUs).
// 2-phase double-buffered staging: stage tile k+1 into buf^1 BEFORE computing
// tile k from buf, one barrier per iteration.
__global__ __launch_bounds__(256) void gemm_bf16_bt(
    const unsigned short* __restrict__ A,
    const unsigned short* __restrict__ B,
    void* __restrict__ Cv, int M, int N, int ld, int Ksub, int c_bf16) {
  __shared__ alignas(16) unsigned short As[2][128 * 32];
  __shared__ alignas(16) unsigned short Bs[2][128 * 32];
  const int tid = threadIdx.x;
  const int m0 = blockIdx.y * 128;
  const int n0 = blockIdx.x * 128;
  const int koff = blockIdx.z * Ksub;
  const int lane = tid & 63;
  const int wave = tid >> 6;
  const int wm = (wave >> 1) * 64;
  const int wn = (wave & 1) * 64;
  const int lrow = lane & 15;
  const int kgrp = lane >> 4;

  const unsigned short* aG = A + (size_t)(m0 + wave * 32 + (lane >> 2)) * ld + (lane & 3) * 8 + koff;
  const unsigned short* bG = B + (size_t)(n0 + wave * 32 + (lane >> 2)) * ld + (lane & 3) * 8 + koff;

  auto stage = [&](int k0, int b) {
    gl_lds16(aG + k0, &As[b][(wave * 32) * 32]);
    gl_lds16(aG + (size_t)16 * ld + k0, &As[b][(wave * 32 + 16) * 32]);
    gl_lds16(bG + k0, &Bs[b][(wave * 32) * 32]);
    gl_lds16(bG + (size_t)16 * ld + k0, &Bs[b][(wave * 32 + 16) * 32]);
  };

  floatx4 acc[4][4];
#pragma unroll
  for (int i = 0; i < 4; i++)
#pragma unroll
    for (int j = 0; j < 4; j++) acc[i][j] = floatx4{0.f, 0.f, 0.f, 0.f};

  stage(0, 0);
  __syncthreads();  // buf0 ready (vmcnt(0) drain emitted before barrier)
  int cur = 0;
  for (int k0 = 0; k0 < Ksub; k0 += 32) {
    if (k0 + 32 < Ksub) stage(k0 + 32, cur ^ 1);  // in flight during compute
    bf16x8 af[4], bfr[4];
#pragma unroll
    for (int i = 0; i < 4; i++)
      af[i] = *reinterpret_cast<const bf16x8*>(&As[cur][(wm + i * 16 + lrow) * 32 + kgrp * 8]);
#pragma unroll
    for (int j = 0; j < 4; j++)
      bfr[j] = *reinterpret_cast<const bf16x8*>(&Bs[cur][(wn + j * 16 + lrow) * 32 + kgrp * 8]);
#pragma unroll
    for (int i = 0; i < 4; i++)
#pragma unroll
      for (int j = 0; j < 4; j++)
        acc[i][j] = mfma16(af[i], bfr[j], acc[i][j]);
    __syncthreads();  // drains next-tile DMA; readers of cur are done (lgkmcnt0)
    cur ^= 1;
  }

  if (c_bf16) {
    unsigned short* C = (unsigned short*)Cv;
#pragma unroll
    for (int i = 0; i < 4; i++) {
      int row = m0 + wm + i * 16 + kgrp * 4;
#pragma unroll
      for (int j = 0; j < 4; j++) {
        int col = n0 + wn + j * 16 + lrow;
#pragma unroll
        for (int r = 0; r < 4; r++)
          C[(size_t)(row + r) * N + col] = f2bf(acc[i][j][r]);
      }
    }
  } else {
    float* C = (float*)Cv + (size_t)blockIdx.z * M * N;
#pragma unroll
    for (int i = 0; i < 4; i++) {
      int row = m0 + wm + i * 16 + kgrp * 4;
#pragma unroll
      for (int j = 0; j < 4; j++) {
        int col = n0 + wn + j * 16 + lrow;
#pragma unroll
        for (int r = 0; r < 4; r++)
          C[(size_t)(row + r) * N + col] = acc[i][j][r];
      }
    }
  }
}

// ---------------- sum of 2 split-K fp32 partials ----------------
__global__ __launch_bounds__(256) void add_out(
    const float* __restrict__ p, float* __restrict__ out, int n4) {
  int i = blockIdx.x * 256 + threadIdx.x;  // float4 index
  if (i >= n4) return;
  float4 a = ((const float4*)p)[i];
  float4 b = ((const float4*)p)[i + n4];
  float4 o;
  o.x = a.x + b.x; o.y = a.y + b.y; o.z = a.z + b.z; o.w = a.w + b.w;
  ((float4*)out)[i] = o;
}

// ---------------- RMSNorm + partial RoPE (per (t, head), D=256) ----------------
__global__ __launch_bounds__(256) void norm_rope(
    const unsigned short* __restrict__ in, const float* __restrict__ w,
    const int* __restrict__ pos, unsigned short* __restrict__ outb,
    int in_rs, int in_hs, int out_rs) {
  const int t = blockIdx.x, h = blockIdx.y, d = threadIdx.x;
  float x = bf2f(in[(size_t)t * in_rs + h * in_hs + d]);
  float ss = x * x;
#pragma unroll
  for (int m = 32; m >= 1; m >>= 1) ss += __shfl_xor(ss, m);
  __shared__ float wsum[4];
  if ((d & 63) == 0) wsum[d >> 6] = ss;
  __syncthreads();
  float tot = (wsum[0] + wsum[1]) + (wsum[2] + wsum[3]);
  float rms = rsqrtf(tot * (1.0f / 256.0f) + EPS_F);
  float y = x * rms * (1.0f + w[d]);
  float o = y;
  if (d < ROT) {
    float partner = __shfl_xor(y, ROT / 2);
    int i = d & (ROT / 2 - 1);
    // theta^(-i/32) = 2^(-i*log2(theta)/32), log2(1e7)=23.2534966642
    float fr = (float)pos[t] * exp2f(-(float)i * (23.2534966642f / 32.0f));
    float c = cosf(fr), s = sinf(fr);
    o = (d < ROT / 2) ? (y * c - partner * s) : (partner * s + y * c);
  }
  outb[(size_t)t * out_rs + h * HD + d] = f2bf(o);
}

// ---------------- V transpose: (T, cols src_off..+512) -> (512, T) ----------------
__global__ __launch_bounds__(256) void vtrans(
    const unsigned short* __restrict__ vin, unsigned short* __restrict__ vT,
    int src_stride, int src_off) {
  int gid = blockIdx.x * 256 + threadIdx.x;  // gid = c*T + t
  int t = gid & (T_LEN - 1);
  int c = gid >> 11;
  vT[gid] = vin[(size_t)t * src_stride + src_off + c];
}

// ---------------- Flash attention (single-tile blocks, 1-barrier loop) ----------------
// Grid (32, 16): block owns ONE 64-row q-tile; t = 31 - blockIdx.x (LPT).
// K AND V double-buffered => single barrier per iteration:
//   barrier -> stage K/V(ib+1 -> buf^1) -> QK(cur) -> P -> PV(cur).
// Hazards: staging targets cur^1; iteration ib-1's reads of cur^1 are
// data-consumed before each wave reaches the barrier; each wave's vmcnt(0)
// at the next barrier drains its own DMAs. Ps is per-wave-private (no
// cross-wave sync needed; compiler orders ds_write->ds_read via lgkmcnt).
// Ps rows padded to 40 elems (80B, b128-aligned): read slots uniform
// (8 lanes / 4-bank slot = optimal for b128), write conflicts spread.
// LDS = 32(K dbuf) + 32(V dbuf) + 5(Ps) = 69KB, 2 blocks/CU.
__global__ __launch_bounds__(256, 2) void attn_fwd(
    const unsigned short* __restrict__ qbf,    // (T, H*D) post norm+rope
    const unsigned short* __restrict__ kbf,    // (T, KV*D) post norm+rope
    const unsigned short* __restrict__ vT,     // (KV*D, T)
    const unsigned short* __restrict__ qkvout, // (T, 9216), gate at h*512+256
    unsigned short* __restrict__ og)           // (T, H*D)
{
  const int t = 31 - (int)blockIdx.x;  // LPT: biggest tile first
  const int h = blockIdx.y;
  const int wv = threadIdx.x >> 6;
  const int lane = threadIdx.x & 63;
  const int lrow = lane & 15;
  const int kgrp = lane >> 4;
  const int kv = h >> 3;  // H/KV = 8
  const int q0 = t * 64 + wv * 16;
  const int nb = t * 2 + 2;  // number of 32-key blocks for this tile

  // K: [key 0..31][dim chunks swizzled: pos = c ^ (key&7)], 2x16KB
  __shared__ alignas(16) unsigned short Ks[2][32 * 256];
  // V: [dim 0..255][key chunks swizzled: pos = c ^ (dim&3)], 2x16KB
  __shared__ alignas(16) unsigned short Vs[2][256 * 32];
  // P: per-wave 16 rows x 32 cols, row stride 40 (80B, 16B-aligned)
  __shared__ alignas(16) unsigned short Ps[4][16 * 40];

  // DMA staging: wave wv handles insts [wv*4, wv*4+4) of 16 total per tile.
  auto stage_k = [&](int kb, int buf) {
#pragma unroll
    for (int i = 0; i < 4; ++i) {
      const int inst = wv * 4 + i;
      const int key_loc = inst * 2 + (lane >> 5);
      const int c = (lane & 31) ^ (key_loc & 7);
      const unsigned short* g =
          kbf + (size_t)(kb + key_loc) * (NKV * HD) + kv * HD + c * 8;
      gl_lds16(g, &Ks[buf][inst * 512]);
    }
  };
  auto stage_v = [&](int kb, int buf) {
#pragma unroll
    for (int i = 0; i < 4; ++i) {
      const int inst = wv * 4 + i;
      const int dim = inst * 16 + (lane >> 2);
      const int c = (lane & 3) ^ (dim & 3);
      const unsigned short* g =
          vT + (size_t)(kv * HD + dim) * T_LEN + kb + c * 8;
      gl_lds16(g, &Vs[buf][inst * 512]);
    }
  };

  // Q A-fragments (global, once)
  bf16x8 qa[8];
  {
    const unsigned short* qr = qbf + (size_t)(q0 + lrow) * (NH * HD) + h * HD + kgrp * 8;
#pragma unroll
    for (int s = 0; s < 8; s++)
      qa[s] = *reinterpret_cast<const bf16x8*>(qr + s * 32);
  }

  float lp[4] = {0.f, 0.f, 0.f, 0.f};
  floatx4 o[16];
#pragma unroll
  for (int dt = 0; dt < 16; dt++) o[dt] = floatx4{0.f, 0.f, 0.f, 0.f};

  stage_k(0, 0);
  stage_v(0, 0);

  for (int ib = 0; ib < nb; ++ib) {
    const int kb = ib * 32;
    const int cur = ib & 1;
    __syncthreads();  // drains DMAs into buf cur; prev-iter reads of cur^1 done
    if (ib + 1 < nb) { stage_k(kb + 32, cur ^ 1); stage_v(kb + 32, cur ^ 1); }

    const bool d = kb <= q0 + 15;

    // ---- S = Q K^T over 2 j-subtiles of 16 keys ----
    floatx4 s0[2];
#pragma unroll
    for (int j = 0; j < 2; j++) s0[j] = floatx4{0.f, 0.f, 0.f, 0.f};
#pragma unroll
    for (int j = 0; j < 2; ++j) {
      const int ks = kb + j * 16;
      if (!(d && (ks <= q0 + 15))) continue;
      bf16x8 kf[8];
#pragma unroll
      for (int s = 0; s < 8; s++)
        kf[s] = *reinterpret_cast<const bf16x8*>(
            &Ks[cur][(j * 16 + lrow) * 256 + (((s * 4 + kgrp) ^ (lrow & 7)) * 8)]);
#pragma unroll
      for (int s = 0; s < 8; s++) s0[j] = mfma16(qa[s], kf[s], s0[j]);
    }

    // ---- P = exp(S*scale) with causal mask (no max subtraction) ----
    if (d) {
#pragma unroll
      for (int r = 0; r < 4; ++r) {
        const int qr = q0 + kgrp * 4 + r;
        float p0 = (kb + lrow <= qr) ? __expf(s0[0][r] * SCALE_F) : 0.f;
        float p1 = (kb + 16 + lrow <= qr) ? __expf(s0[1][r] * SCALE_F) : 0.f;
        lp[r] += p0 + p1;
        Ps[wv][(kgrp * 4 + r) * 40 + lrow] = f2bf(p0);
        Ps[wv][(kgrp * 4 + r) * 40 + 16 + lrow] = f2bf(p1);
      }
    }

    // ---- O += P V (Ps is wave-private: lgkmcnt ordering suffices) ----
    if (d) {
      bf16x8 pa = *reinterpret_cast<const bf16x8*>(&Ps[wv][lrow * 40 + kgrp * 8]);
      const unsigned short* vsb = &Vs[cur][0];
#pragma unroll
      for (int dt = 0; dt < 16; ++dt) {
        const int dd = dt * 16 + lrow;
        bf16x8 bv = *reinterpret_cast<const bf16x8*>(
            &vsb[dd * 32 + ((kgrp ^ (lrow & 3)) * 8)]);
        o[dt] = mfma16(pa, bv, o[dt]);
      }
    }
  }

  // ---- reduce l across the 16 row-lanes ----
#pragma unroll
  for (int r = 0; r < 4; ++r) {
#pragma unroll
    for (int m = 8; m >= 1; m >>= 1) lp[r] += __shfl_xor(lp[r], m);
  }

  // ---- epilogue: o/l * sigmoid(gate) ----
#pragma unroll
  for (int r = 0; r < 4; ++r) {
    const int row = q0 + kgrp * 4 + r;
    const float inv_l = 1.0f / lp[r];
    const unsigned short* grow = qkvout + (size_t)row * 9216 + h * 512 + 256;
    unsigned short* orow = og + (size_t)row * (NH * HD) + h * HD;
#pragma unroll
    for (int dt = 0; dt < 16; dt++) {
      int dim = dt * 16 + lrow;
      float g = bf2f(grow[dim]);
      float val = o[dt][r] * inv_l;
      val *= 1.0f / (1.0f + __expf(-g));
      orow[dim] = f2bf(val);
    }
  }
}

extern "C" void kernel_launch(void* const* d_in, const int* in_sizes, int n_in,
                              void* d_out, int out_size, void* d_ws, size_t ws_size,
                              hipStream_t stream) {
  const int* positions = (const int*)d_in[0];
  const float* hidden = (const float*)d_in[1];
  const float* wq = (const float*)d_in[2];
  const float* wk = (const float*)d_in[3];
  const float* wv = (const float*)d_in[4];
  const float* wo = (const float*)d_in[5];
  const float* qnw = (const float*)d_in[6];
  const float* knw = (const float*)d_in[7];
  float* out = (float*)d_out;

  char* ws = (char*)d_ws;
  size_t off = 0;
  auto alloc = [&](size_t elems) -> unsigned short* {
    unsigned short* p = (unsigned short*)(ws + off);
    off += (elems * 2 + 255) & ~(size_t)255;
    return p;
  };
  unsigned short* hsb    = alloc((size_t)T_LEN * HID_DIM);
  unsigned short* qkvwb  = alloc((size_t)9216 * HID_DIM);
  unsigned short* wob    = alloc((size_t)HID_DIM * NH * HD);
  unsigned short* qkvout = alloc((size_t)T_LEN * 9216);
  unsigned short* qbf    = alloc((size_t)T_LEN * NH * HD);
  unsigned short* kbf    = alloc((size_t)T_LEN * NKV * HD);
  unsigned short* vTb    = alloc((size_t)NKV * HD * T_LEN);
  unsigned short* og     = alloc((size_t)T_LEN * NH * HD);
  // split-K partials (2 x 2048x2048 fp32 = 33.5MB) alias hsb+qkvwb (46MB),
  // which are dead after GEMM1. GEMM2 reads og/wob only - no overlap.
  float* part = (float*)ws;

  cvt_all<<<30720, 256, 0, stream>>>(hidden, wq, wk, wv, wo, hsb, qkvwb, wob);

  gemm_bf16_bt<<<dim3(72, 16, 1), 256, 0, stream>>>(hsb, qkvwb, qkvout, 2048, 9216, 2048, 2048, 1);

  norm_rope<<<dim3(T_LEN, NH), 256, 0, stream>>>(qkvout, qnw, positions, qbf, 9216, 512, NH * HD);
  norm_rope<<<dim3(T_LEN, NKV), 256, 0, stream>>>(qkvout + 8192, knw, positions, kbf, 9216, HD, NKV * HD);
  vtrans<<<(NKV * HD * T_LEN) / 256, 256, 0, stream>>>(qkvout, vTb, 9216, 8704);

  attn_fwd<<<dim3(32, NH), 256, 0, stream>>>(qbf, kbf, vTb, qkvout, og);

  // split-K=2: grid.z=2 -> 512 blocks (2/CU) instead of 256 (1/CU);
  // each z writes an fp32 partial over K-half 2048.
  gemm_bf16_bt<<<dim3(16, 16, 2), 256, 0, stream>>>(og, wob, part, 2048, 2048, 4096, 2048, 0);
  add_out<<<4096, 256, 0, stream>>>(part, out, 1048576);
}

// Round 7
// 443.706 us; speedup vs baseline: 1.0313x; 1.0313x over previous
//
#include <hip/hip_runtime.h>
#include <hip/hip_bf16.h>

#define T_LEN 2048
#define HID_DIM 2048
#define NH 16
#define NKV 2
#define HD 256
#define ROT 64
#define EPS_F 1e-6f
#define SCALE_F 0.0625f   // 256^-0.5
#define THETA_F 10000000.0f

typedef __bf16 bf16x8 __attribute__((ext_vector_type(8)));
typedef float floatx4 __attribute__((ext_vector_type(4)));

__device__ __forceinline__ unsigned short f2bf(float x) {
  unsigned int u = __float_as_uint(x);
  unsigned int rounding = 0x7FFFu + ((u >> 16) & 1u);
  return (unsigned short)((u + rounding) >> 16);
}
__device__ __forceinline__ float bf2f(unsigned short u) {
  return __uint_as_float(((unsigned int)u) << 16);
}
__device__ __forceinline__ floatx4 mfma16(bf16x8 a, bf16x8 b, floatx4 c) {
  return __builtin_amdgcn_mfma_f32_16x16x32_bf16(a, b, c, 0, 0, 0);
}
// async global->LDS DMA, 16B/lane: lds dest = wave-uniform base + lane*16
__device__ __forceinline__ void gl_lds16(const unsigned short* g, unsigned short* l) {
  __builtin_amdgcn_global_load_lds(
      (const __attribute__((address_space(1))) unsigned int*)g,
      (__attribute__((address_space(3))) unsigned int*)l, 16, 0, 0);
}

// ---------------- merged fp32 -> bf16 conversion (5 segments, f4-vectorized) ----------------
__global__ __launch_bounds__(256) void cvt_all(
    const float* __restrict__ hs, const float* __restrict__ wq,
    const float* __restrict__ wk, const float* __restrict__ wv,
    const float* __restrict__ wo, unsigned short* __restrict__ hsb,
    unsigned short* __restrict__ qkvwb, unsigned short* __restrict__ wob) {
  int i = blockIdx.x * 256 + threadIdx.x;  // float4 index, total 7864320
  const float4* s4;
  ushort4* d4;
  int j;
  if (i < 1048576) { s4 = (const float4*)hs; d4 = (ushort4*)hsb; j = i; }
  else if (i < 5242880) { s4 = (const float4*)wq; d4 = (ushort4*)qkvwb; j = i - 1048576; }
  else if (i < 5505024) { s4 = (const float4*)wk; d4 = (ushort4*)qkvwb + 4194304; j = i - 5242880; }
  else if (i < 5767168) { s4 = (const float4*)wv; d4 = (ushort4*)qkvwb + 4456448; j = i - 5505024; }
  else { s4 = (const float4*)wo; d4 = (ushort4*)wob; j = i - 5767168; }
  float4 v = s4[j];
  ushort4 o;
  o.x = f2bf(v.x); o.y = f2bf(v.y); o.z = f2bf(v.z); o.w = f2bf(v.w);
  d4[j] = o;
}

// ---------------- bf16 GEMM: C[M,N] = A[M,K] * B[N,K]^T ----------------
// ld = row stride of A and B (elements); Ksub = K-range per z-slice.
// blockIdx.z selects K-slice [z*Ksub, (z+1)*Ksub); fp32 path writes partial
// z to Cv + z*M*N (split-K for TLP when M/128 * N/128 < 2*256 CUs).
// 2-phase double-buffered staging: stage tile k+1 into buf^1 BEFORE computing
// tile k from buf, one barrier per iteration.
// vTout (bf16 path only): blocks with n0 >= 8704 (the V columns; 8704 is a
// multiple of the 128-col tile so the branch is block-uniform) write their
// output TRANSPOSED to vTout[(col-8704)*T + row] instead of C -- this fuses
// the V transpose into the epilogue and eliminates the vtrans kernel (whose
// strided read over-fetched ~32x). Nothing else reads qkvout's V region.
__global__ __launch_bounds__(256) void gemm_bf16_bt(
    const unsigned short* __restrict__ A,
    const unsigned short* __restrict__ B,
    void* __restrict__ Cv, int M, int N, int ld, int Ksub, int c_bf16,
    unsigned short* __restrict__ vTout) {
  __shared__ alignas(16) unsigned short As[2][128 * 32];
  __shared__ alignas(16) unsigned short Bs[2][128 * 32];
  const int tid = threadIdx.x;
  const int m0 = blockIdx.y * 128;
  const int n0 = blockIdx.x * 128;
  const int koff = blockIdx.z * Ksub;
  const int lane = tid & 63;
  const int wave = tid >> 6;
  const int wm = (wave >> 1) * 64;
  const int wn = (wave & 1) * 64;
  const int lrow = lane & 15;
  const int kgrp = lane >> 4;

  const unsigned short* aG = A + (size_t)(m0 + wave * 32 + (lane >> 2)) * ld + (lane & 3) * 8 + koff;
  const unsigned short* bG = B + (size_t)(n0 + wave * 32 + (lane >> 2)) * ld + (lane & 3) * 8 + koff;

  auto stage = [&](int k0, int b) {
    gl_lds16(aG + k0, &As[b][(wave * 32) * 32]);
    gl_lds16(aG + (size_t)16 * ld + k0, &As[b][(wave * 32 + 16) * 32]);
    gl_lds16(bG + k0, &Bs[b][(wave * 32) * 32]);
    gl_lds16(bG + (size_t)16 * ld + k0, &Bs[b][(wave * 32 + 16) * 32]);
  };

  floatx4 acc[4][4];
#pragma unroll
  for (int i = 0; i < 4; i++)
#pragma unroll
    for (int j = 0; j < 4; j++) acc[i][j] = floatx4{0.f, 0.f, 0.f, 0.f};

  stage(0, 0);
  __syncthreads();  // buf0 ready (vmcnt(0) drain emitted before barrier)
  int cur = 0;
  for (int k0 = 0; k0 < Ksub; k0 += 32) {
    if (k0 + 32 < Ksub) stage(k0 + 32, cur ^ 1);  // in flight during compute
    bf16x8 af[4], bfr[4];
#pragma unroll
    for (int i = 0; i < 4; i++)
      af[i] = *reinterpret_cast<const bf16x8*>(&As[cur][(wm + i * 16 + lrow) * 32 + kgrp * 8]);
#pragma unroll
    for (int j = 0; j < 4; j++)
      bfr[j] = *reinterpret_cast<const bf16x8*>(&Bs[cur][(wn + j * 16 + lrow) * 32 + kgrp * 8]);
#pragma unroll
    for (int i = 0; i < 4; i++)
#pragma unroll
      for (int j = 0; j < 4; j++)
        acc[i][j] = mfma16(af[i], bfr[j], acc[i][j]);
    __syncthreads();  // drains next-tile DMA; readers of cur are done (lgkmcnt0)
    cur ^= 1;
  }

  if (c_bf16) {
    unsigned short* C = (unsigned short*)Cv;
    const bool vtile = (vTout != nullptr) && (n0 >= 8704);  // block-uniform
#pragma unroll
    for (int i = 0; i < 4; i++) {
      int row = m0 + wm + i * 16 + kgrp * 4;
#pragma unroll
      for (int j = 0; j < 4; j++) {
        int col = n0 + wn + j * 16 + lrow;
        if (vtile) {
          unsigned short* vrow = vTout + (size_t)(col - 8704) * T_LEN + row;
#pragma unroll
          for (int r = 0; r < 4; r++) vrow[r] = f2bf(acc[i][j][r]);
        } else {
#pragma unroll
          for (int r = 0; r < 4; r++)
            C[(size_t)(row + r) * N + col] = f2bf(acc[i][j][r]);
        }
      }
    }
  } else {
    float* C = (float*)Cv + (size_t)blockIdx.z * M * N;
#pragma unroll
    for (int i = 0; i < 4; i++) {
      int row = m0 + wm + i * 16 + kgrp * 4;
#pragma unroll
      for (int j = 0; j < 4; j++) {
        int col = n0 + wn + j * 16 + lrow;
#pragma unroll
        for (int r = 0; r < 4; r++)
          C[(size_t)(row + r) * N + col] = acc[i][j][r];
      }
    }
  }
}

// ---------------- sum of 2 split-K fp32 partials ----------------
__global__ __launch_bounds__(256) void add_out(
    const float* __restrict__ p, float* __restrict__ out, int n4) {
  int i = blockIdx.x * 256 + threadIdx.x;  // float4 index
  if (i >= n4) return;
  float4 a = ((const float4*)p)[i];
  float4 b = ((const float4*)p)[i + n4];
  float4 o;
  o.x = a.x + b.x; o.y = a.y + b.y; o.z = a.z + b.z; o.w = a.w + b.w;
  ((float4*)out)[i] = o;
}

// ---------------- RMSNorm + partial RoPE (per (t, head), D=256) ----------------
__global__ __launch_bounds__(256) void norm_rope(
    const unsigned short* __restrict__ in, const float* __restrict__ w,
    const int* __restrict__ pos, unsigned short* __restrict__ outb,
    int in_rs, int in_hs, int out_rs) {
  const int t = blockIdx.x, h = blockIdx.y, d = threadIdx.x;
  float x = bf2f(in[(size_t)t * in_rs + h * in_hs + d]);
  float ss = x * x;
#pragma unroll
  for (int m = 32; m >= 1; m >>= 1) ss += __shfl_xor(ss, m);
  __shared__ float wsum[4];
  if ((d & 63) == 0) wsum[d >> 6] = ss;
  __syncthreads();
  float tot = (wsum[0] + wsum[1]) + (wsum[2] + wsum[3]);
  float rms = rsqrtf(tot * (1.0f / 256.0f) + EPS_F);
  float y = x * rms * (1.0f + w[d]);
  float o = y;
  if (d < ROT) {
    float partner = __shfl_xor(y, ROT / 2);
    int i = d & (ROT / 2 - 1);
    // theta^(-i/32) = 2^(-i*log2(theta)/32), log2(1e7)=23.2534966642
    float fr = (float)pos[t] * exp2f(-(float)i * (23.2534966642f / 32.0f));
    float c = cosf(fr), s = sinf(fr);
    o = (d < ROT / 2) ? (y * c - partner * s) : (partner * s + y * c);
  }
  outb[(size_t)t * out_rs + h * HD + d] = f2bf(o);
}

// ---------------- Flash attention (R5-proven, single-tile blocks) ----------------
// Grid (32, 16): each block owns ONE 64-row q-tile; t = 31 - blockIdx.x (LPT).
// LDS 52KB => up to 3 blocks/CU; independent blocks' waves hide each other's
// barrier/DMA-drain latency. (R6's 1-barrier/K-dbuf variant regressed 5%;
// this 2-barrier structure is the measured optimum at this block shape.)
__global__ __launch_bounds__(256, 2) void attn_fwd(
    const unsigned short* __restrict__ qbf,    // (T, H*D) post norm+rope
    const unsigned short* __restrict__ kbf,    // (T, KV*D) post norm+rope
    const unsigned short* __restrict__ vT,     // (KV*D, T)
    const unsigned short* __restrict__ qkvout, // (T, 9216), gate at h*512+256
    unsigned short* __restrict__ og)           // (T, H*D)
{
  const int t = 31 - (int)blockIdx.x;  // LPT: biggest tile first
  const int h = blockIdx.y;
  const int wv = threadIdx.x >> 6;
  const int lane = threadIdx.x & 63;
  const int lrow = lane & 15;
  const int kgrp = lane >> 4;
  const int kv = h >> 3;  // H/KV = 8
  const int q0 = t * 64 + wv * 16;
  const int nb = t * 2 + 2;  // number of 32-key blocks for this tile

  // K: [key 0..31][dim chunks swizzled: pos = c ^ (key&7)], 16KB
  __shared__ alignas(16) unsigned short Ks[32 * 256];
  // V: [dim 0..255][key chunks swizzled: pos = c ^ (dim&3)], 2x16KB
  __shared__ alignas(16) unsigned short Vs[2][256 * 32];
  // P: per-wave 16x32 bf16
  __shared__ alignas(16) unsigned short Ps[4][16 * 32];

  // DMA staging: wave wv handles insts [wv*4, wv*4+4) of 16 total per tile.
  auto stage_k = [&](int kb) {
#pragma unroll
    for (int i = 0; i < 4; ++i) {
      const int inst = wv * 4 + i;
      const int key_loc = inst * 2 + (lane >> 5);
      const int c = (lane & 31) ^ (key_loc & 7);
      const unsigned short* g =
          kbf + (size_t)(kb + key_loc) * (NKV * HD) + kv * HD + c * 8;
      gl_lds16(g, &Ks[inst * 512]);
    }
  };
  auto stage_v = [&](int kb, int buf) {
#pragma unroll
    for (int i = 0; i < 4; ++i) {
      const int inst = wv * 4 + i;
      const int dim = inst * 16 + (lane >> 2);
      const int c = (lane & 3) ^ (dim & 3);
      const unsigned short* g =
          vT + (size_t)(kv * HD + dim) * T_LEN + kb + c * 8;
      gl_lds16(g, &Vs[buf][inst * 512]);
    }
  };

  // Q A-fragments (global, once)
  bf16x8 qa[8];
  {
    const unsigned short* qr = qbf + (size_t)(q0 + lrow) * (NH * HD) + h * HD + kgrp * 8;
#pragma unroll
    for (int s = 0; s < 8; s++)
      qa[s] = *reinterpret_cast<const bf16x8*>(qr + s * 32);
  }

  float lp[4] = {0.f, 0.f, 0.f, 0.f};
  floatx4 o[16];
#pragma unroll
  for (int dt = 0; dt < 16; dt++) o[dt] = floatx4{0.f, 0.f, 0.f, 0.f};

  stage_k(0);
  stage_v(0, 0);

  for (int ib = 0; ib < nb; ++ib) {
    const int kb = ib * 32;
    __syncthreads();  // drains K(ib) + V(ib) DMAs; protects V buffer reuse
    if (ib + 1 < nb) stage_v(kb + 32, (ib + 1) & 1);

    const bool d = kb <= q0 + 15;

    // ---- S = Q K^T over 2 j-subtiles of 16 keys ----
    floatx4 s0[2];
#pragma unroll
    for (int j = 0; j < 2; j++) s0[j] = floatx4{0.f, 0.f, 0.f, 0.f};
#pragma unroll
    for (int j = 0; j < 2; ++j) {
      const int ks = kb + j * 16;
      if (!(d && (ks <= q0 + 15))) continue;
      bf16x8 kf[8];
#pragma unroll
      for (int s = 0; s < 8; s++)
        kf[s] = *reinterpret_cast<const bf16x8*>(
            &Ks[(j * 16 + lrow) * 256 + (((s * 4 + kgrp) ^ (lrow & 7)) * 8)]);
#pragma unroll
      for (int s = 0; s < 8; s++) s0[j] = mfma16(qa[s], kf[s], s0[j]);
    }

    // ---- P = exp(S*scale) with causal mask (no max subtraction) ----
    if (d) {
#pragma unroll
      for (int r = 0; r < 4; ++r) {
        const int qr = q0 + kgrp * 4 + r;
        float p0 = (kb + lrow <= qr) ? __expf(s0[0][r] * SCALE_F) : 0.f;
        float p1 = (kb + 16 + lrow <= qr) ? __expf(s0[1][r] * SCALE_F) : 0.f;
        lp[r] += p0 + p1;
        Ps[wv][(kgrp * 4 + r) * 32 + lrow] = f2bf(p0);
        Ps[wv][(kgrp * 4 + r) * 32 + 16 + lrow] = f2bf(p1);
      }
    }

    __syncthreads();  // all waves done reading Ks (also drains V(ib+1) DMA)
    if (ib + 1 < nb) stage_k(kb + 32);

    // ---- O += P V ----
    if (d) {
      bf16x8 pa = *reinterpret_cast<const bf16x8*>(&Ps[wv][lrow * 32 + kgrp * 8]);
      const unsigned short* vsb = &Vs[ib & 1][0];
#pragma unroll
      for (int dt = 0; dt < 16; ++dt) {
        const int dd = dt * 16 + lrow;
        bf16x8 bv = *reinterpret_cast<const bf16x8*>(
            &vsb[dd * 32 + ((kgrp ^ (lrow & 3)) * 8)]);
        o[dt] = mfma16(pa, bv, o[dt]);
      }
    }
  }

  // ---- reduce l across the 16 row-lanes ----
#pragma unroll
  for (int r = 0; r < 4; ++r) {
#pragma unroll
    for (int m = 8; m >= 1; m >>= 1) lp[r] += __shfl_xor(lp[r], m);
  }

  // ---- epilogue: o/l * sigmoid(gate) ----
#pragma unroll
  for (int r = 0; r < 4; ++r) {
    const int row = q0 + kgrp * 4 + r;
    const float inv_l = 1.0f / lp[r];
    const unsigned short* grow = qkvout + (size_t)row * 9216 + h * 512 + 256;
    unsigned short* orow = og + (size_t)row * (NH * HD) + h * HD;
#pragma unroll
    for (int dt = 0; dt < 16; dt++) {
      int dim = dt * 16 + lrow;
      float g = bf2f(grow[dim]);
      float val = o[dt][r] * inv_l;
      val *= 1.0f / (1.0f + __expf(-g));
      orow[dim] = f2bf(val);
    }
  }
}

extern "C" void kernel_launch(void* const* d_in, const int* in_sizes, int n_in,
                              void* d_out, int out_size, void* d_ws, size_t ws_size,
                              hipStream_t stream) {
  const int* positions = (const int*)d_in[0];
  const float* hidden = (const float*)d_in[1];
  const float* wq = (const float*)d_in[2];
  const float* wk = (const float*)d_in[3];
  const float* wv = (const float*)d_in[4];
  const float* wo = (const float*)d_in[5];
  const float* qnw = (const float*)d_in[6];
  const float* knw = (const float*)d_in[7];
  float* out = (float*)d_out;

  char* ws = (char*)d_ws;
  size_t off = 0;
  auto alloc = [&](size_t elems) -> unsigned short* {
    unsigned short* p = (unsigned short*)(ws + off);
    off += (elems * 2 + 255) & ~(size_t)255;
    return p;
  };
  unsigned short* hsb    = alloc((size_t)T_LEN * HID_DIM);
  unsigned short* qkvwb  = alloc((size_t)9216 * HID_DIM);
  unsigned short* wob    = alloc((size_t)HID_DIM * NH * HD);
  unsigned short* qkvout = alloc((size_t)T_LEN * 9216);
  unsigned short* qbf    = alloc((size_t)T_LEN * NH * HD);
  unsigned short* kbf    = alloc((size_t)T_LEN * NKV * HD);
  unsigned short* vTb    = alloc((size_t)NKV * HD * T_LEN);
  unsigned short* og     = alloc((size_t)T_LEN * NH * HD);
  // split-K partials (2 x 2048x2048 fp32 = 33.5MB) alias hsb+qkvwb (46MB),
  // which are dead after GEMM1. GEMM2 reads og/wob only - no overlap.
  float* part = (float*)ws;

  cvt_all<<<30720, 256, 0, stream>>>(hidden, wq, wk, wv, wo, hsb, qkvwb, wob);

  // GEMM1 writes Q/K/gate to qkvout; V columns (>=8704) go transposed
  // straight to vTb (fused vtrans).
  gemm_bf16_bt<<<dim3(72, 16, 1), 256, 0, stream>>>(hsb, qkvwb, qkvout, 2048, 9216, 2048, 2048, 1, vTb);

  norm_rope<<<dim3(T_LEN, NH), 256, 0, stream>>>(qkvout, qnw, positions, qbf, 9216, 512, NH * HD);
  norm_rope<<<dim3(T_LEN, NKV), 256, 0, stream>>>(qkvout + 8192, knw, positions, kbf, 9216, HD, NKV * HD);

  attn_fwd<<<dim3(32, NH), 256, 0, stream>>>(qbf, kbf, vTb, qkvout, og);

  // split-K=2: grid.z=2 -> 512 blocks (2/CU) instead of 256 (1/CU);
  // each z writes an fp32 partial over K-half 2048.
  gemm_bf16_bt<<<dim3(16, 16, 2), 256, 0, stream>>>(og, wob, part, 2048, 2048, 4096, 2048, 0, nullptr);
  add_out<<<4096, 256, 0, stream>>>(part, out, 1048576);
}